// Round 2
// baseline (29.640 us; speedup 1.0000x reference)
//
#include <hip/hip_runtime.h>

// Problem constants: BS=2048, P=32, C=14
constexpr int NB = 2048;
constexpr int NP = 32;
constexpr int NC = 14;
constexpr int ELEMS_PER_B = NP * NP * NC;   // 14336 floats per batch slice
constexpr int NT = 448;                      // 7 waves
constexpr int NITER = 8;                     // 448 threads * 4 floats * 8 iters = 14336

// Flat element f = it*1792 + 4*tid + k  (1792 = 14*128, so it-term is channel-neutral)
//   ch      = (4*tid+k) % 14      (constant per thread-lane)
//   posBase = (4*tid+k) / 14      in [0,128)
//   pos     = it*128 + posBase ;  j = pos&31 = posBase&31 (const) ; i = 4*it + (posBase>>5)
// (ch, posBase) is a bijection over the 1792 thread-lane slots -> LDS [14][128] reduction.
__global__ __launch_bounds__(NT) void loss_main(
    const float* __restrict__ y_pred,
    const float* __restrict__ eta,
    const float* __restrict__ p_in,
    const float* __restrict__ bbox,
    float* __restrict__ partial)
{
    const int b   = blockIdx.x;
    const int tid = threadIdx.x;

    __shared__ int   win[NC][4];             // x0, y0, x1, y1
    __shared__ float rAll[NC * 128];
    __shared__ float r1[NC * 128];
    __shared__ float r3[NC * 128];
    __shared__ float lossArr[NC];

    if (tid < NC) {
        const float* bb = bbox + ((size_t)b * NC + tid) * 4;
        int x0 = (int)(bb[0] * (float)NP);   // trunc toward zero == astype(int32)
        int y0 = (int)(bb[1] * (float)NP);
        int w  = (int)(bb[2] * (float)NP);
        int h  = (int)(bb[3] * (float)NP);
        win[tid][0] = x0;
        win[tid][1] = y0;
        win[tid][2] = x0 + w;
        win[tid][3] = y0 + h;
    }
    __syncthreads();

    int  ch[4], pB[4], ihi[4], ry0[4], ry1[4];
    bool col[4];
    #pragma unroll
    for (int k = 0; k < 4; ++k) {
        int f0 = 4 * tid + k;
        ch[k]  = f0 % NC;
        pB[k]  = f0 / NC;
        int j  = pB[k] & 31;
        ihi[k] = pB[k] >> 5;
        ry0[k] = win[ch[k]][1];
        ry1[k] = win[ch[k]][3];
        col[k] = (j >= win[ch[k]][0]) && (j < win[ch[k]][2]);
    }

    float aAll[4] = {1.f, 1.f, 1.f, 1.f};
    float a1[4]   = {1.f, 1.f, 1.f, 1.f};
    float a3[4]   = {1.f, 1.f, 1.f, 1.f};

    const float4* base = reinterpret_cast<const float4*>(y_pred + (size_t)b * ELEMS_PER_B);

    #pragma unroll
    for (int it = 0; it < NITER; ++it) {
        const float4 v = base[it * NT + tid];
        const float vv[4] = {v.x, v.y, v.z, v.w};
        #pragma unroll
        for (int k = 0; k < 4; ++k) {
            const int i = 4 * it + ihi[k];
            float yp0 = fminf(1.f, vv[k]);
            float t0  = fminf(1.f, 1.f - yp0);
            float yp  = fmaf(yp0, 0.02f, 0.98f);
            float t   = fmaf(t0,  0.02f, 0.98f);
            aAll[k] *= t;
            bool m = col[k] && (i >= ry0[k]) && (i < ry1[k]);
            a1[k] *= m ? yp : 1.f;
            a3[k] *= m ? t  : 1.f;
        }
    }

    #pragma unroll
    for (int k = 0; k < 4; ++k) {
        const int a = ch[k] * 128 + pB[k];
        rAll[a] = aAll[k];
        r1[a]   = a1[k];
        r3[a]   = a3[k];
    }
    __syncthreads();

    // 7-step multiply tree over the 128 partials per channel
    #pragma unroll
    for (int s = 64; s >= 1; s >>= 1) {
        for (int idx = tid; idx < NC * s; idx += NT) {
            const int c = idx / s, m = idx - c * s;
            const int a = c * 128 + m, a2 = a + s;
            rAll[a] *= rAll[a2];
            r1[a]   *= r1[a2];
            r3[a]   *= r3[a2];
        }
        __syncthreads();
    }

    if (tid < NC) {
        float Pall = rAll[tid * 128];        // prod of tmp over all (i,j)
        float P1   = r1[tid * 128];          // prod of yp inside bbox
        float P3   = r3[tid * 128];          // prod of tmp inside bbox
        float pyx  = 1.f - Pall;
        float pyxb = P1 * Pall / P3 + 1e-10f;
        float e  = eta[(size_t)b * NC + tid];
        float pp = p_in[(size_t)b * NC + tid];
        float loss = -e * logf(pyxb)
                     - (1.f - e) * pp * logf(pyx)
                     - (1.f - e) * (1.f - pp) * logf(Pall);
        lossArr[tid] = loss;
    }
    __syncthreads();

    if (tid == 0) {
        float s = 0.f;
        #pragma unroll
        for (int c = 0; c < NC; ++c) s += lossArr[c];
        partial[b] = s;
    }
}

// Deterministic fixed-order final reduction; overwrites d_out.
__global__ __launch_bounds__(1024) void reduce_partials(
    const float* __restrict__ partial, float* __restrict__ out)
{
    __shared__ float s[1024];
    const int t = threadIdx.x;
    s[t] = partial[t] + partial[t + 1024];
    __syncthreads();
    for (int st = 512; st >= 1; st >>= 1) {
        if (t < st) s[t] += s[t + st];
        __syncthreads();
    }
    if (t == 0) out[0] = s[0] / (float)NB;
}

extern "C" void kernel_launch(void* const* d_in, const int* in_sizes, int n_in,
                              void* d_out, int out_size, void* d_ws, size_t ws_size,
                              hipStream_t stream)
{
    const float* y_pred = (const float*)d_in[0];
    const float* eta    = (const float*)d_in[1];
    const float* p_in   = (const float*)d_in[2];
    const float* bbox   = (const float*)d_in[3];
    float* partial = (float*)d_ws;           // 2048 floats = 8 KB scratch
    float* out     = (float*)d_out;

    loss_main<<<NB, NT, 0, stream>>>(y_pred, eta, p_in, bbox, partial);
    reduce_partials<<<1, 1024, 0, stream>>>(partial, out);
}